// Round 2
// baseline (397.190 us; speedup 1.0000x reference)
//
#include <hip/hip_runtime.h>
#include <hip/hip_bf16.h>
#include <hip/hip_cooperative_groups.h>

namespace cg = cooperative_groups;

#define DEV static __device__ __forceinline__

constexpr int B=16, N=128, FIN=128, FOUT=256, EOUT=64, BINW=14, BOUT=64, CI=64, L1=256;

// ---- scratch layout in d_ws (float offsets) ----
constexpr int O_H   = 0;                       // [B,N,FOUT]
constexpr int O_S   = O_H  + B*N*FOUT;         // [B,N]
constexpr int O_SU  = O_S  + B*N;
constexpr int O_SV  = O_SU + B*N;
constexpr int O_ATT = O_SV + B*N;              // [B,N,N]
constexpr int O_ZF  = O_ATT+ B*N*N;            // [B,N,CI]
constexpr int O_ZB  = O_ZF + B*N*CI;
constexpr int O_RF  = O_ZB + B*N*CI;
constexpr int O_RB  = O_RF + B*N*CI;
constexpr int O_H1  = O_RB + B*N*CI;           // [B,N,FOUT]

DEV float bf16_to_f32(unsigned short u){
  unsigned int x = ((unsigned int)u) << 16; float f;
  __builtin_memcpy(&f, &x, 4); return f;
}
DEV void bf2x(unsigned int u, float& lo, float& hi){
  unsigned int a = u << 16, b = u & 0xFFFF0000u;
  __builtin_memcpy(&lo, &a, 4); __builtin_memcpy(&hi, &b, 4);
}
DEV float lrelu(float x){ return x > 0.f ? x : 0.01f * x; }
DEV float bcastf(float v, int lane){
  return __builtin_bit_cast(float, __builtin_amdgcn_readlane(__builtin_bit_cast(int, v), lane));
}
DEV float ldf(const void* p, int i, int m){
  return m ? bf16_to_f32(((const unsigned short*)p)[i]) : ((const float*)p)[i];
}
// block-parallel dtype detect (bf16 ~100% of sampled exps in [100,140]; f32 ~58%)
DEV int blk_mode(const void* x, int nt, int tid){
  const unsigned short* u = (const unsigned short*)x;
  int e = (u[tid & 255] >> 7) & 0xFF;
  int cnt = __syncthreads_count(e >= 100 && e <= 140);
  return cnt * 4 >= nt * 3;
}

struct FA {
  const void *x, *Wp, *Ap, *fccw, *fcw;                 // stage 1
  const int  *adj;
  const void *we, *wfcw, *wfcb, *fcb, *fccb;            // stage 2
  const void *wihf, *bihf, *bhhf, *wihb, *bihb, *bhhb;  // stage 2 (z)
  const void *whhf, *whhb;                              // stage 3
  const void *fcow, *fcob;                              // stage 4
  float *ws;
  void  *dout;
};

// One cooperative kernel: 256 blocks x 256 threads, 1 block/CU.
// Stage1 h/P/Q/su/sv -> sync -> Stage2 att+z (4 row-pairs/block) -> sync ->
// Stage3 RNN(32 blks) + h1(224 blks) -> sync -> Stage4 output GEMM.
__global__ __launch_bounds__(256, 1) void k_fused(FA A){
  cg::grid_group gg = cg::this_grid();
  __shared__ __align__(16) float smem[8192];   // 32 KB, aliased per stage
  int blk = blockIdx.x, tid = threadIdx.x;
  int mode = blk_mode(A.x, 256, tid);
  float* ws = A.ws;
  const float* R = ws;

  // ---------------- stage 1: h = x@W ; s ; P,Q ; su/sv ----------------
  {
    int b = blk >> 4, i0 = (blk & 15) * 8;
    float* xl   = smem;          // 8*FIN  = 1024
    float* hrow = smem + 1024;   // 8*FOUT = 2048
    float* pl   = smem + 3072;   // 8*EOUT = 512
    float* ql   = smem + 3584;   // 512
    float* red  = smem + 4096;   // 32
    if (mode){
      const unsigned short* xu = (const unsigned short*)A.x + (size_t)(b*N + i0)*FIN;
      for (int t = tid; t < 8*FIN/8; t += 256){
        uint4 u4 = ((const uint4*)xu)[t];
        float* o = &xl[t*8];
        bf2x(u4.x,o[0],o[1]); bf2x(u4.y,o[2],o[3]); bf2x(u4.z,o[4],o[5]); bf2x(u4.w,o[6],o[7]);
      }
    } else {
      const float* xf = (const float*)A.x + (size_t)(b*N + i0)*FIN;
      for (int t4 = tid; t4 < 8*FIN/4; t4 += 256)
        *(float4*)&xl[t4*4] = ((const float4*)xf)[t4];
    }
    __syncthreads();
    int f = tid;
    float acc[8] = {0,0,0,0,0,0,0,0};
    if (mode){
      const unsigned short* Wu = (const unsigned short*)A.Wp;
      for (int c = 0; c < FIN; c += 4){
        float w0 = bf16_to_f32(Wu[(c+0)*FOUT + f]);
        float w1 = bf16_to_f32(Wu[(c+1)*FOUT + f]);
        float w2 = bf16_to_f32(Wu[(c+2)*FOUT + f]);
        float w3 = bf16_to_f32(Wu[(c+3)*FOUT + f]);
        #pragma unroll
        for (int r = 0; r < 8; ++r){
          float4 x4 = *(const float4*)&xl[r*FIN + c];
          acc[r] += x4.x*w0 + x4.y*w1 + x4.z*w2 + x4.w*w3;
        }
      }
    } else {
      const float* Wf = (const float*)A.Wp;
      for (int c = 0; c < FIN; c += 4){
        float w0 = Wf[(c+0)*FOUT + f];
        float w1 = Wf[(c+1)*FOUT + f];
        float w2 = Wf[(c+2)*FOUT + f];
        float w3 = Wf[(c+3)*FOUT + f];
        #pragma unroll
        for (int r = 0; r < 8; ++r){
          float4 x4 = *(const float4*)&xl[r*FIN + c];
          acc[r] += x4.x*w0 + x4.y*w1 + x4.z*w2 + x4.w*w3;
        }
      }
    }
    float fw = ldf(A.fccw, f, mode);
    #pragma unroll
    for (int r = 0; r < 8; ++r){
      ws[O_H + (b*N + i0 + r)*FOUT + f] = acc[r];
      hrow[r*FOUT + f] = acc[r];
    }
    #pragma unroll
    for (int r = 0; r < 8; ++r){
      float v = acc[r] * fw;
      for (int off = 32; off; off >>= 1) v += __shfl_down(v, off);
      if ((tid & 63) == 0) red[(tid >> 6)*8 + r] = v;
    }
    __syncthreads();
    if (tid < 8){
      float s = red[tid] + red[8+tid] + red[16+tid] + red[24+tid];
      ws[O_S + b*N + i0 + tid] = s;
    }
    // P/Q into LDS (4 waves: which = P/Q, hh = row-half)
    {
      int o = tid & 63, which = (tid >> 6) & 1, hh = tid >> 7;
      float a4[4] = {0.f,0.f,0.f,0.f};
      if (mode){
        const unsigned short* Au = (const unsigned short*)A.Ap;
        for (int c = 0; c < FOUT; c += 4){
          float w0 = bf16_to_f32(Au[(which*FOUT + c+0)*EOUT + o]);
          float w1 = bf16_to_f32(Au[(which*FOUT + c+1)*EOUT + o]);
          float w2 = bf16_to_f32(Au[(which*FOUT + c+2)*EOUT + o]);
          float w3 = bf16_to_f32(Au[(which*FOUT + c+3)*EOUT + o]);
          #pragma unroll
          for (int r = 0; r < 4; ++r){
            float4 h4 = *(const float4*)&hrow[(hh*4+r)*FOUT + c];
            a4[r] += h4.x*w0 + h4.y*w1 + h4.z*w2 + h4.w*w3;
          }
        }
      } else {
        const float* Af = (const float*)A.Ap;
        for (int c = 0; c < FOUT; c += 4){
          float w0 = Af[(which*FOUT + c+0)*EOUT + o];
          float w1 = Af[(which*FOUT + c+1)*EOUT + o];
          float w2 = Af[(which*FOUT + c+2)*EOUT + o];
          float w3 = Af[(which*FOUT + c+3)*EOUT + o];
          #pragma unroll
          for (int r = 0; r < 4; ++r){
            float4 h4 = *(const float4*)&hrow[(hh*4+r)*FOUT + c];
            a4[r] += h4.x*w0 + h4.y*w1 + h4.z*w2 + h4.w*w3;
          }
        }
      }
      float* dst = which ? ql : pl;
      #pragma unroll
      for (int r = 0; r < 4; ++r) dst[(hh*4+r)*EOUT + o] = a4[r];
    }
    __syncthreads();
    // su rows i0..i0+7 ; sv pairs (sv[r]==sv[r+64])
    {
      int o = tid & 63, w = tid >> 6;
      float fw2 = ldf(A.fcw, o, mode);
      float s1 = lrelu(pl[w*EOUT + o]     + ql[w*EOUT + o])     * fw2;
      float s2 = lrelu(pl[(w+4)*EOUT + o] + ql[(w+4)*EOUT + o]) * fw2;
      float s3 = lrelu(pl[(2*w)*EOUT + o] + ql[(2*w+1)*EOUT + o]) * fw2;
      for (int off = 32; off; off >>= 1){
        s1 += __shfl_down(s1, off); s2 += __shfl_down(s2, off); s3 += __shfl_down(s3, off);
      }
      if (o == 0){
        ws[O_SU + b*N + i0 + w]     = s1;
        ws[O_SU + b*N + i0 + w + 4] = s2;
        int r1 = (i0 + 2*w) >> 1;
        ws[O_SV + b*N + r1]      = s3;
        ws[O_SV + b*N + r1 + 64] = s3;
      }
    }
  }
  __threadfence();
  gg.sync();

  // ---------------- stage 2: att + hn_pre + z (4 row-pairs per block) -----
  {
    float (*wel)[N*BINW] = (float (*)[N*BINW])smem;        // 2*1792 = 3584
    float (*hnp)[N]      = (float (*)[N])(smem + 3584);    // 2*128
    float* wfcwl = smem + 3840;                            // 896
    float* wfcbl = smem + 4736;                            // 64
    float* fcw2l = smem + 4800;                            // 64
    float (*red2)[2]     = (float (*)[2])(smem + 4864);    // 4
    for (int t = tid; t < BINW*BOUT; t += 256) wfcwl[t] = ldf(A.wfcw, t, mode);
    if (tid < BOUT){ wfcbl[tid] = ldf(A.wfcb, tid, mode); fcw2l[tid] = ldf(A.fcw, EOUT + tid, mode); }
    int half = tid >> 7, j = tid & 127, wv = (tid >> 6) & 1;
    float fcbv = ldf(A.fcb, 0, mode), fccbv = ldf(A.fccb, 0, mode);
    for (int pr = 0; pr < 4; ++pr){
      int tau = blk*8 + pr*2 + half;
      int b = tau >> 7, i = tau & 127;
      if (mode){
        const unsigned short* weu = (const unsigned short*)A.we + (size_t)(b*N + i)*N*BINW;
        for (int t = j; t < N*BINW/8; t += 128){
          uint4 q = ((const uint4*)weu)[t];
          float* o = &wel[half][t*8];
          bf2x(q.x,o[0],o[1]); bf2x(q.y,o[2],o[3]); bf2x(q.z,o[4],o[5]); bf2x(q.w,o[6],o[7]);
        }
      } else {
        const float* wef = (const float*)A.we + (size_t)(b*N + i)*N*BINW;
        for (int t4 = j; t4 < N*BINW/4; t4 += 128)
          *(float4*)&wel[half][t4*4] = ((const float4*)wef)[t4];
      }
      __syncthreads();
      float wr[BINW];
      #pragma unroll
      for (int t = 0; t < BINW; ++t) wr[t] = wel[half][j*BINW + t];
      float wcon = 0.f;
      for (int o = 0; o < BOUT; o += 4){
        float4 bb = *(const float4*)&wfcbl[o];
        float w0 = bb.x, w1 = bb.y, w2 = bb.z, w3 = bb.w;
        #pragma unroll
        for (int t = 0; t < BINW; ++t){
          float4 w4 = *(const float4*)&wfcwl[t*BOUT + o];
          w0 = fmaf(wr[t], w4.x, w0); w1 = fmaf(wr[t], w4.y, w1);
          w2 = fmaf(wr[t], w4.z, w2); w3 = fmaf(wr[t], w4.w, w3);
        }
        float4 f4 = *(const float4*)&fcw2l[o];
        wcon += lrelu(w0)*f4.x + lrelu(w1)*f4.y + lrelu(w2)*f4.z + lrelu(w3)*f4.w;
      }
      float econ = (i < 64) ? R[O_SU + b*N + 2*i + (j >= 64 ? 1 : 0)]
                            : R[O_SV + b*N + j];
      float etot = econ + wcon + fcbv;
      float m = (A.adj[(b*N + i)*N + j] > 0) ? etot : -9e15f;
      float mx = m;
      for (int off = 32; off; off >>= 1) mx = fmaxf(mx, __shfl_xor(mx, off));
      if ((tid & 63) == 0) red2[half][wv] = mx;
      __syncthreads();
      mx = fmaxf(red2[half][0], red2[half][1]);
      float ev = expf(m - mx);
      float sum = ev;
      for (int off = 32; off; off >>= 1) sum += __shfl_xor(sum, off);
      __syncthreads();
      if ((tid & 63) == 0) red2[half][wv] = sum;
      __syncthreads();
      sum = red2[half][0] + red2[half][1];
      float att = ev / sum;
      ws[O_ATT + (b*N + i)*N + j] = att;
      float sbi = R[O_S + b*N + i];
      hnp[half][j] = lrelu(att * sbi + fccbv);
      __syncthreads();
      // z[b,i,c] both directions (per half: 2 waves = 2 directions)
      {
        int d = wv, c = tid & 63;
        float acc = ldf(d ? A.bihb : A.bihf, c, mode) + ldf(d ? A.bhhb : A.bhhf, c, mode);
        const void* wihp = d ? A.wihb : A.wihf;
        if (mode){
          const uint4* wq = (const uint4*)((const unsigned short*)wihp + c*N);
          #pragma unroll 4
          for (int k = 0; k < N; k += 8){
            uint4 q = wq[k >> 3];
            float w0,w1,w2,w3,w4,w5,w6,w7;
            bf2x(q.x,w0,w1); bf2x(q.y,w2,w3); bf2x(q.z,w4,w5); bf2x(q.w,w6,w7);
            float4 h0 = *(const float4*)&hnp[half][k];
            float4 h1 = *(const float4*)&hnp[half][k+4];
            acc += h0.x*w0 + h0.y*w1 + h0.z*w2 + h0.w*w3
                 + h1.x*w4 + h1.y*w5 + h1.z*w6 + h1.w*w7;
          }
        } else {
          const float* wf = (const float*)wihp + c*N;
          #pragma unroll 8
          for (int k = 0; k < N; k += 4){
            float4 h4 = *(const float4*)&hnp[half][k];
            float4 w4 = *(const float4*)&wf[k];
            acc += h4.x*w4.x + h4.y*w4.y + h4.z*w4.z + h4.w*w4.w;
          }
        }
        ws[(d ? O_ZB : O_ZF) + (b*N + i)*CI + c] = acc;
      }
      __syncthreads();   // protect hnp before next pair overwrites
    }
  }
  __threadfence();
  gg.sync();

  // ---------------- stage 3: RNN chains (blocks 0..31) + h1 (32..255) -----
  {
    float* sh = smem;   // 8192 floats (32 KB)
    if (blk < 32){
      int d = blk >> 4, b = blk & 15;
      const int zb = (d ? O_ZB : O_ZF) + b*N*CI;
      const int ob = (d ? O_RB : O_RF) + b*N*CI;
      for (int it = tid; it < N*CI/4; it += 256)
        *(float4*)&sh[it*4] = *(const float4*)&ws[zb + it*4];
      __syncthreads();
      if (tid < 64){
        int c = tid;
        const void* whhp = d ? A.whhb : A.whhf;
        float wreg[CI];
        if (mode){
          const uint4* wq = (const uint4*)((const unsigned short*)whhp + c*CI);
          #pragma unroll
          for (int k = 0; k < CI; k += 8){
            uint4 q = wq[k >> 3];
            bf2x(q.x,wreg[k+0],wreg[k+1]); bf2x(q.y,wreg[k+2],wreg[k+3]);
            bf2x(q.z,wreg[k+4],wreg[k+5]); bf2x(q.w,wreg[k+6],wreg[k+7]);
          }
        } else {
          const float* wf = (const float*)whhp + c*CI;
          #pragma unroll
          for (int k = 0; k < CI; k += 4){
            float4 w4 = *(const float4*)&wf[k];
            wreg[k]=w4.x; wreg[k+1]=w4.y; wreg[k+2]=w4.z; wreg[k+3]=w4.w;
          }
        }
        const int step = d ? -1 : 1;
        int tt = d ? (N-1) : 0;
        float hv = 0.f;
        float z = sh[tt*CI + c];    // single wave: DS ops in-order
        for (int t = 0; t < N; ++t){
          int ti = tt + step; ti = ti < 0 ? 0 : (ti > N-1 ? N-1 : ti);
          float znext = sh[ti*CI + c];
          float s[CI];
          #pragma unroll
          for (int k = 0; k < CI; ++k) s[k] = bcastf(hv, k);
#if __has_builtin(__builtin_amdgcn_sched_barrier)
          __builtin_amdgcn_sched_barrier(0);
#endif
          float a0 = z, a1 = 0.f, a2 = 0.f, a3 = 0.f;
          #pragma unroll
          for (int k = 0; k < CI; k += 4){
            a0 = fmaf(s[k+0], wreg[k+0], a0);
            a1 = fmaf(s[k+1], wreg[k+1], a1);
            a2 = fmaf(s[k+2], wreg[k+2], a2);
            a3 = fmaf(s[k+3], wreg[k+3], a3);
          }
          float x = (a0+a1)+(a2+a3);
          x = fminf(15.f, fmaxf(-15.f, x));
          float p = __expf(2.f * x);
          hv = (p - 1.f) * __builtin_amdgcn_rcpf(p + 1.f);
          sh[tt*CI + c] = hv;
          z = znext;
          tt += step;
        }
      }
      __syncthreads();
      for (int it = tid; it < N*CI/4; it += 256)
        *(float4*)&ws[ob + it*4] = *(const float4*)&sh[it*4];
    } else {
      for (int task = blk - 32; task < 256; task += 224){
        int b = task >> 4, i0 = (task & 15) * 8;
        int f = tid;
        __syncthreads();
        for (int t = tid; t < 8*N; t += 256){
          int r = t >> 7, k = t & 127;
          sh[k*8 + r] = R[O_ATT + (b*N + i0 + r)*N + k];
        }
        __syncthreads();
        float acc[8] = {0,0,0,0,0,0,0,0};
        for (int k = 0; k < N; ++k){
          float hv = R[O_H + (b*N + k)*FOUT + f];
          float4 a0 = *(const float4*)&sh[k*8];
          float4 a1 = *(const float4*)&sh[k*8 + 4];
          acc[0] += a0.x*hv; acc[1] += a0.y*hv; acc[2] += a0.z*hv; acc[3] += a0.w*hv;
          acc[4] += a1.x*hv; acc[5] += a1.y*hv; acc[6] += a1.z*hv; acc[7] += a1.w*hv;
        }
        #pragma unroll
        for (int r = 0; r < 8; ++r)
          ws[O_H1 + (b*N + i0 + r)*FOUT + f] = acc[r];
      }
    }
  }
  __threadfence();
  gg.sync();

  // ---------------- stage 4: out = elu(cat(...) @ fco_w + fco_b) ----------
  {
    int b = blk >> 4, i0 = (blk & 15) * 8;
    constexpr int KW = 2*CI + FOUT;  // 416
    float* inl = smem;               // 8*KW = 3328
    __syncthreads();                 // smem handoff from stage 3 aliasing
    for (int t = tid; t < 8*2*CI; t += 256){
      int r = t >> 7, k = t & 127;
      int row = b*N + i0 + r;
      inl[r*KW + k] = (k < CI) ? lrelu(R[O_RF + row*CI + k])
                               : lrelu(R[O_RB + row*CI + (k - CI)]);
    }
    for (int t = tid; t < 8*FOUT; t += 256){
      int r = t >> 8, k = t & 255;
      inl[r*KW + 2*CI + k] = R[O_H1 + (b*N + i0 + r)*FOUT + k];
    }
    __syncthreads();
    int l = tid;
    float bias = ldf(A.fcob, l, mode);
    float acc[8];
    #pragma unroll
    for (int r = 0; r < 8; ++r) acc[r] = bias;
    if (mode){
      const unsigned short* fu = (const unsigned short*)A.fcow;
      for (int k = 0; k < KW; k += 4){
        float w0 = bf16_to_f32(fu[(k+0)*L1 + l]);
        float w1 = bf16_to_f32(fu[(k+1)*L1 + l]);
        float w2 = bf16_to_f32(fu[(k+2)*L1 + l]);
        float w3 = bf16_to_f32(fu[(k+3)*L1 + l]);
        #pragma unroll
        for (int r = 0; r < 8; ++r){
          float4 v = *(const float4*)&inl[r*KW + k];
          acc[r] += v.x*w0 + v.y*w1 + v.z*w2 + v.w*w3;
        }
      }
    } else {
      const float* ff = (const float*)A.fcow;
      for (int k = 0; k < KW; k += 4){
        float w0 = ff[(k+0)*L1 + l];
        float w1 = ff[(k+1)*L1 + l];
        float w2 = ff[(k+2)*L1 + l];
        float w3 = ff[(k+3)*L1 + l];
        #pragma unroll
        for (int r = 0; r < 8; ++r){
          float4 v = *(const float4*)&inl[r*KW + k];
          acc[r] += v.x*w0 + v.y*w1 + v.z*w2 + v.w*w3;
        }
      }
    }
    #pragma unroll
    for (int r = 0; r < 8; ++r){
      float o = acc[r] > 0.f ? acc[r] : expm1f(acc[r]);
      int idx = (b*N + i0 + r)*L1 + l;
      if (mode) ((__hip_bfloat16*)A.dout)[idx] = __float2bfloat16(o);
      else      ((float*)A.dout)[idx] = o;
    }
  }
}

extern "C" void kernel_launch(void* const* d_in, const int* in_sizes, int n_in,
                              void* d_out, int out_size, void* d_ws, size_t ws_size,
                              hipStream_t stream){
  (void)in_sizes; (void)n_in; (void)out_size; (void)ws_size;
  FA fa;
  fa.x    = d_in[0];  fa.adj  = (const int*)d_in[1]; fa.we  = d_in[2];
  fa.Wp   = d_in[3];  fa.Ap   = d_in[4];
  fa.wfcw = d_in[5];  fa.wfcb = d_in[6];
  fa.fcw  = d_in[7];  fa.fcb  = d_in[8];
  fa.fccw = d_in[9];  fa.fccb = d_in[10];
  fa.wihf = d_in[11]; fa.whhf = d_in[12]; fa.bihf = d_in[13]; fa.bhhf = d_in[14];
  fa.wihb = d_in[15]; fa.whhb = d_in[16]; fa.bihb = d_in[17]; fa.bhhb = d_in[18];
  fa.fcow = d_in[19]; fa.fcob = d_in[20];
  fa.ws   = (float*)d_ws;
  fa.dout = d_out;
  void* kp[] = { &fa };
  hipLaunchCooperativeKernel((void*)k_fused, dim3(256), dim3(256), kp, 0, stream);
}

// Round 3
// 212.203 us; speedup vs baseline: 1.8717x; 1.8717x over previous
//
#include <hip/hip_runtime.h>
#include <hip/hip_bf16.h>

#define DEV static __device__ __forceinline__

constexpr int B=16, N=128, FIN=128, FOUT=256, EOUT=64, BINW=14, BOUT=64, CI=64, L1=256;

// ---- scratch layout in d_ws (float offsets) ----
constexpr int O_H   = 0;                       // [B,N,FOUT]
constexpr int O_S   = O_H  + B*N*FOUT;         // [B,N]
constexpr int O_SU  = O_S  + B*N;
constexpr int O_SV  = O_SU + B*N;
constexpr int O_ATT = O_SV + B*N;              // [B,N,N]
constexpr int O_ZF  = O_ATT+ B*N*N;            // [B,N,CI]
constexpr int O_ZB  = O_ZF + B*N*CI;
constexpr int O_RF  = O_ZB + B*N*CI;
constexpr int O_RB  = O_RF + B*N*CI;
constexpr int O_H1  = O_RB + B*N*CI;           // [B,N,FOUT]

DEV float bf16_to_f32(unsigned short u){
  unsigned int x = ((unsigned int)u) << 16; float f;
  __builtin_memcpy(&f, &x, 4); return f;
}
DEV void bf2x(unsigned int u, float& lo, float& hi){
  unsigned int a = u << 16, b = u & 0xFFFF0000u;
  __builtin_memcpy(&lo, &a, 4); __builtin_memcpy(&hi, &b, 4);
}
DEV float lrelu(float x){ return x > 0.f ? x : 0.01f * x; }
DEV float bcastf(float v, int lane){
  return __builtin_bit_cast(float, __builtin_amdgcn_readlane(__builtin_bit_cast(int, v), lane));
}
DEV float ldf(const void* p, int i, int m){
  return m ? bf16_to_f32(((const unsigned short*)p)[i]) : ((const float*)p)[i];
}
// block-parallel dtype detect (bf16 ~100% of sampled exps in [100,140]; f32 ~58%)
DEV int blk_mode(const void* x, int nt, int tid){
  const unsigned short* u = (const unsigned short*)x;
  int e = (u[tid & 255] >> 7) & 0xFF;
  int cnt = __syncthreads_count(e >= 100 && e <= 140);
  return cnt * 4 >= nt * 3;
}

// Prefetch table: warm L3 (evicted every iteration by the 256MB ws poison)
// for tensors consumed by LATER kernels (K2/K3/K4), concurrent with K1.
struct PF { const void* p[7]; int b32[7]; int b16[7]; int insz[7]; };

// K1: h = x@W ; s = h·fcc_w ; P,Q (LDS only) ; su/sv fused (sv[r]==sv[r+64])
// blocks 0..511: real work (4 rows each). blocks 512..1023: L3-warming prefetch.
__global__ __launch_bounds__(256, 2) void k_h_pq(const void* __restrict__ xr,
                                                 const void* __restrict__ Wp,
                                                 const void* __restrict__ Ap,
                                                 const void* __restrict__ fccwp,
                                                 const void* __restrict__ fcwp,
                                                 PF pf,
                                                 float* __restrict__ ws){
  int blk = blockIdx.x, tid = threadIdx.x;
  if (blk >= 512){
    // ---- L3 warming: stream-read future kernels' inputs at full BW ----
    int mode = blk_mode(xr, 256, tid);
    int pid = blk - 512;
    unsigned int acc = 0;
    for (int e = 0; e < 7; ++e){
      int bytes = mode ? pf.b16[e] : pf.b32[e];
      if (pf.insz[e] > 0 && pf.insz[e] < bytes) bytes = pf.insz[e];  // clamp (safe either unit)
      const uint4* p = (const uint4*)pf.p[e];
      int n16 = bytes >> 4;
      for (int t = pid*256 + tid; t < n16; t += 512*256){
        uint4 v = p[t];
        acc ^= v.x ^ v.y ^ v.z ^ v.w;
      }
    }
    asm volatile("" :: "v"(acc));   // keep loads live
    return;
  }
  int b = blk >> 5, i0 = (blk & 31) * 4;
  __shared__ __align__(16) float xl[4*FIN];
  __shared__ __align__(16) float hrow[4*FOUT];
  __shared__ __align__(16) float pl[4*EOUT];
  __shared__ __align__(16) float ql[4*EOUT];
  __shared__ float red[16];
  int mode = blk_mode(xr, 256, tid);
  if (mode){
    const unsigned short* xu = (const unsigned short*)xr + (size_t)(b*N + i0)*FIN;
    for (int t = tid; t < 4*FIN/8; t += 256){
      uint4 u4 = ((const uint4*)xu)[t];
      float* o = &xl[t*8];
      bf2x(u4.x,o[0],o[1]); bf2x(u4.y,o[2],o[3]); bf2x(u4.z,o[4],o[5]); bf2x(u4.w,o[6],o[7]);
    }
  } else {
    const float* xf = (const float*)xr + (size_t)(b*N + i0)*FIN;
    for (int t4 = tid; t4 < 4*FIN/4; t4 += 256)
      *(float4*)&xl[t4*4] = ((const float4*)xf)[t4];
  }
  __syncthreads();
  int f = tid;
  float acc[4] = {0,0,0,0};
  if (mode){
    const unsigned short* Wu = (const unsigned short*)Wp;
    #pragma unroll 4
    for (int c = 0; c < FIN; c += 4){
      float w0 = bf16_to_f32(Wu[(c+0)*FOUT + f]);
      float w1 = bf16_to_f32(Wu[(c+1)*FOUT + f]);
      float w2 = bf16_to_f32(Wu[(c+2)*FOUT + f]);
      float w3 = bf16_to_f32(Wu[(c+3)*FOUT + f]);
      #pragma unroll
      for (int r = 0; r < 4; ++r){
        float4 x4 = *(const float4*)&xl[r*FIN + c];
        acc[r] += x4.x*w0 + x4.y*w1 + x4.z*w2 + x4.w*w3;
      }
    }
  } else {
    const float* Wf = (const float*)Wp;
    #pragma unroll 4
    for (int c = 0; c < FIN; c += 4){
      float w0 = Wf[(c+0)*FOUT + f];
      float w1 = Wf[(c+1)*FOUT + f];
      float w2 = Wf[(c+2)*FOUT + f];
      float w3 = Wf[(c+3)*FOUT + f];
      #pragma unroll
      for (int r = 0; r < 4; ++r){
        float4 x4 = *(const float4*)&xl[r*FIN + c];
        acc[r] += x4.x*w0 + x4.y*w1 + x4.z*w2 + x4.w*w3;
      }
    }
  }
  float fw = ldf(fccwp, f, mode);
  #pragma unroll
  for (int r = 0; r < 4; ++r){
    ws[O_H + (b*N + i0 + r)*FOUT + f] = acc[r];
    hrow[r*FOUT + f] = acc[r];
  }
  #pragma unroll
  for (int r = 0; r < 4; ++r){
    float v = acc[r] * fw;
    for (int off = 32; off; off >>= 1) v += __shfl_down(v, off);
    if ((tid & 63) == 0) red[(tid >> 6)*4 + r] = v;
  }
  __syncthreads();
  if (tid < 4){
    float s = red[tid] + red[4+tid] + red[8+tid] + red[12+tid];
    ws[O_S + b*N + i0 + tid] = s;
  }
  // P/Q into LDS (4 waves: which = P/Q, hh = row-half); hrow reads wave-uniform
  {
    int o = tid & 63, which = (tid >> 6) & 1, hh = tid >> 7;
    float a2[2] = {0.f,0.f};
    if (mode){
      const unsigned short* Au = (const unsigned short*)Ap;
      #pragma unroll 2
      for (int c = 0; c < FOUT; c += 4){
        float w0 = bf16_to_f32(Au[(which*FOUT + c+0)*EOUT + o]);
        float w1 = bf16_to_f32(Au[(which*FOUT + c+1)*EOUT + o]);
        float w2 = bf16_to_f32(Au[(which*FOUT + c+2)*EOUT + o]);
        float w3 = bf16_to_f32(Au[(which*FOUT + c+3)*EOUT + o]);
        #pragma unroll
        for (int r = 0; r < 2; ++r){
          float4 h4 = *(const float4*)&hrow[(hh*2+r)*FOUT + c];
          a2[r] += h4.x*w0 + h4.y*w1 + h4.z*w2 + h4.w*w3;
        }
      }
    } else {
      const float* Af = (const float*)Ap;
      #pragma unroll 2
      for (int c = 0; c < FOUT; c += 4){
        float w0 = Af[(which*FOUT + c+0)*EOUT + o];
        float w1 = Af[(which*FOUT + c+1)*EOUT + o];
        float w2 = Af[(which*FOUT + c+2)*EOUT + o];
        float w3 = Af[(which*FOUT + c+3)*EOUT + o];
        #pragma unroll
        for (int r = 0; r < 2; ++r){
          float4 h4 = *(const float4*)&hrow[(hh*2+r)*FOUT + c];
          a2[r] += h4.x*w0 + h4.y*w1 + h4.z*w2 + h4.w*w3;
        }
      }
    }
    float* dst = which ? ql : pl;
    #pragma unroll
    for (int r = 0; r < 2; ++r) dst[(hh*2+r)*EOUT + o] = a2[r];
  }
  __syncthreads();
  // su for rows i0..i0+3 ; sv for pairs (value keyed by j2=(2r)&127; sv[r]==sv[r+64])
  {
    int o = tid & 63, w = tid >> 6;
    float fw2 = ldf(fcwp, o, mode);
    int w2 = (w < 2) ? w : 0;            // waves 2,3 compute a dummy s3 (not stored)
    float s1 = lrelu(pl[w*EOUT + o]        + ql[w*EOUT + o])        * fw2;
    float s3 = lrelu(pl[(2*w2)*EOUT + o]   + ql[(2*w2+1)*EOUT + o]) * fw2;
    for (int off = 32; off; off >>= 1){
      s1 += __shfl_down(s1, off); s3 += __shfl_down(s3, off);
    }
    if (o == 0){
      ws[O_SU + b*N + i0 + w] = s1;
      if (w < 2){
        int r1 = (i0 >> 1) + w;
        ws[O_SV + b*N + r1]      = s3;
        ws[O_SV + b*N + r1 + 64] = s3;
      }
    }
  }
}

struct AttArgs { const void *we,*x,*wfcw,*wfcb,*fcw,*fcb,*fccb,*wihf,*bihf,*bhhf,*wihb,*bihb,*bhhb; };

// K2: per block: TWO (b,i) rows. edge-MLP + mask + softmax -> att ; hn_pre ; z
__global__ __launch_bounds__(256) void k_att(AttArgs A, const int* __restrict__ adj,
                                             float* __restrict__ ws){
  int blk = blockIdx.x, tid = threadIdx.x;
  int half = tid >> 7, j = tid & 127, wv = (tid >> 6) & 1;
  int tau = blk*2 + half;
  int b = tau >> 7, i = tau & 127;
  __shared__ __align__(16) float wel[2][N*BINW];
  __shared__ __align__(16) float hnp[2][N];
  __shared__ __align__(16) float wfcwl[BINW*BOUT];
  __shared__ __align__(16) float wfcbl[BOUT];
  __shared__ __align__(16) float fcw2l[BOUT];
  __shared__ float red2[2][2];
  int mode = blk_mode(A.x, 256, tid);
  for (int t = tid; t < BINW*BOUT; t += 256) wfcwl[t] = ldf(A.wfcw, t, mode);
  if (tid < BOUT){ wfcbl[tid] = ldf(A.wfcb, tid, mode); fcw2l[tid] = ldf(A.fcw, EOUT + tid, mode); }
  if (mode){
    const unsigned short* weu = (const unsigned short*)A.we + (size_t)(b*N + i)*N*BINW;
    for (int t = j; t < N*BINW/8; t += 128){
      uint4 q = ((const uint4*)weu)[t];
      float* o = &wel[half][t*8];
      bf2x(q.x,o[0],o[1]); bf2x(q.y,o[2],o[3]); bf2x(q.z,o[4],o[5]); bf2x(q.w,o[6],o[7]);
    }
  } else {
    const float* wef = (const float*)A.we + (size_t)(b*N + i)*N*BINW;
    for (int t4 = j; t4 < N*BINW/4; t4 += 128)
      *(float4*)&wel[half][t4*4] = ((const float4*)wef)[t4];
  }
  __syncthreads();
  float wr[BINW];
  #pragma unroll
  for (int t = 0; t < BINW; ++t) wr[t] = wel[half][j*BINW + t];
  float wcon = 0.f;
  for (int o = 0; o < BOUT; o += 4){
    float4 bb = *(const float4*)&wfcbl[o];
    float w0 = bb.x, w1 = bb.y, w2 = bb.z, w3 = bb.w;
    #pragma unroll
    for (int t = 0; t < BINW; ++t){
      float4 w4 = *(const float4*)&wfcwl[t*BOUT + o];
      w0 = fmaf(wr[t], w4.x, w0); w1 = fmaf(wr[t], w4.y, w1);
      w2 = fmaf(wr[t], w4.z, w2); w3 = fmaf(wr[t], w4.w, w3);
    }
    float4 f4 = *(const float4*)&fcw2l[o];
    wcon += lrelu(w0)*f4.x + lrelu(w1)*f4.y + lrelu(w2)*f4.z + lrelu(w3)*f4.w;
  }
  const float* R = ws;
  float econ = (i < 64) ? R[O_SU + b*N + 2*i + (j >= 64 ? 1 : 0)]
                        : R[O_SV + b*N + j];
  float etot = econ + wcon + ldf(A.fcb, 0, mode);
  float m = (adj[(b*N + i)*N + j] > 0) ? etot : -9e15f;
  float mx = m;
  for (int off = 32; off; off >>= 1) mx = fmaxf(mx, __shfl_xor(mx, off));
  if ((tid & 63) == 0) red2[half][wv] = mx;
  __syncthreads();
  mx = fmaxf(red2[half][0], red2[half][1]);
  float ev = expf(m - mx);
  float sum = ev;
  for (int off = 32; off; off >>= 1) sum += __shfl_xor(sum, off);
  __syncthreads();
  if ((tid & 63) == 0) red2[half][wv] = sum;
  __syncthreads();
  sum = red2[half][0] + red2[half][1];
  float att = ev / sum;
  ws[O_ATT + (b*N + i)*N + j] = att;
  float sbi = R[O_S + b*N + i];
  hnp[half][j] = lrelu(att * sbi + ldf(A.fccb, 0, mode));
  __syncthreads();
  // z[b,i,c] both directions (per half: 2 waves = 2 directions)
  {
    int d = wv, c = tid & 63;
    float acc = ldf(d ? A.bihb : A.bihf, c, mode) + ldf(d ? A.bhhb : A.bhhf, c, mode);
    const void* wihp = d ? A.wihb : A.wihf;
    if (mode){
      const uint4* wq = (const uint4*)((const unsigned short*)wihp + c*N);
      #pragma unroll 4
      for (int k = 0; k < N; k += 8){
        uint4 q = wq[k >> 3];
        float w0,w1,w2,w3,w4,w5,w6,w7;
        bf2x(q.x,w0,w1); bf2x(q.y,w2,w3); bf2x(q.z,w4,w5); bf2x(q.w,w6,w7);
        float4 h0 = *(const float4*)&hnp[half][k];
        float4 h1 = *(const float4*)&hnp[half][k+4];
        acc += h0.x*w0 + h0.y*w1 + h0.z*w2 + h0.w*w3
             + h1.x*w4 + h1.y*w5 + h1.z*w6 + h1.w*w7;
      }
    } else {
      const float* wf = (const float*)wihp + c*N;
      #pragma unroll 8
      for (int k = 0; k < N; k += 4){
        float4 h4 = *(const float4*)&hnp[half][k];
        float4 w4 = *(const float4*)&wf[k];
        acc += h4.x*w4.x + h4.y*w4.y + h4.z*w4.z + h4.w*w4.w;
      }
    }
    ws[(d ? O_ZB : O_ZF) + (b*N + i)*CI + c] = acc;
  }
}

// K3: blocks 0..31: serial RNN chains (wave 0).  blocks 32..543: h1 = att@h (4 rows each).
// Independent work -> no sync needed; h1 hides under the chain's latency.
__global__ __launch_bounds__(256, 1) void k_rnn_h1(const void* __restrict__ xr,
                                                   const void* __restrict__ whhf,
                                                   const void* __restrict__ whhb,
                                                   float* __restrict__ ws){
  __shared__ __align__(16) float sh[N*CI];   // rnn: z/h buffer (32 KB); h1: attT (first 2 KB)
  int blk = blockIdx.x, tid = threadIdx.x;
  int mode = blk_mode(xr, 256, tid);
  const float* R = ws;
  if (blk < 32){
    int d = blk >> 4, b = blk & 15;
    const int zb = (d ? O_ZB : O_ZF) + b*N*CI;
    const int ob = (d ? O_RB : O_RF) + b*N*CI;
    for (int it = tid; it < N*CI/4; it += 256)
      *(float4*)&sh[it*4] = *(const float4*)&ws[zb + it*4];
    __syncthreads();
    if (tid < 64){
      int c = tid;
      const void* whhp = d ? whhb : whhf;
      float wreg[CI];
      if (mode){
        const uint4* wq = (const uint4*)((const unsigned short*)whhp + c*CI);
        #pragma unroll
        for (int k = 0; k < CI; k += 8){
          uint4 q = wq[k >> 3];
          bf2x(q.x,wreg[k+0],wreg[k+1]); bf2x(q.y,wreg[k+2],wreg[k+3]);
          bf2x(q.z,wreg[k+4],wreg[k+5]); bf2x(q.w,wreg[k+6],wreg[k+7]);
        }
      } else {
        const float* wf = (const float*)whhp + c*CI;
        #pragma unroll
        for (int k = 0; k < CI; k += 4){
          float4 w4 = *(const float4*)&wf[k];
          wreg[k]=w4.x; wreg[k+1]=w4.y; wreg[k+2]=w4.z; wreg[k+3]=w4.w;
        }
      }
      const int step = d ? -1 : 1;
      int tt = d ? (N-1) : 0;
      float hv = 0.f;
      float z = sh[tt*CI + c];    // single wave: DS ops in-order, no barrier needed
      for (int t = 0; t < N; ++t){
        int ti = tt + step; ti = ti < 0 ? 0 : (ti > N-1 ? N-1 : ti);
        float znext = sh[ti*CI + c];
        float s[CI];
        #pragma unroll
        for (int k = 0; k < CI; ++k) s[k] = bcastf(hv, k);   // batched readlanes
#if __has_builtin(__builtin_amdgcn_sched_barrier)
        __builtin_amdgcn_sched_barrier(0);
#endif
        float a0 = z, a1 = 0.f, a2 = 0.f, a3 = 0.f;
        #pragma unroll
        for (int k = 0; k < CI; k += 4){
          a0 = fmaf(s[k+0], wreg[k+0], a0);
          a1 = fmaf(s[k+1], wreg[k+1], a1);
          a2 = fmaf(s[k+2], wreg[k+2], a2);
          a3 = fmaf(s[k+3], wreg[k+3], a3);
        }
        float x = (a0+a1)+(a2+a3);
        x = fminf(15.f, fmaxf(-15.f, x));
        float p = __expf(2.f * x);
        hv = (p - 1.f) * __builtin_amdgcn_rcpf(p + 1.f);
        sh[tt*CI + c] = hv;
        z = znext;
        tt += step;
      }
    }
    __syncthreads();
    for (int it = tid; it < N*CI/4; it += 256)
      *(float4*)&ws[ob + it*4] = *(const float4*)&sh[it*4];
  } else {
    int task = blk - 32;                 // 0..511, 4 rows each
    int b = task >> 5, i0 = (task & 31) * 4;
    int f = tid;
    for (int t = tid; t < 4*N; t += 256){
      int r = t >> 7, k = t & 127;
      sh[k*4 + r] = R[O_ATT + (b*N + i0 + r)*N + k];
    }
    __syncthreads();
    float acc[4] = {0,0,0,0};
    #pragma unroll 4
    for (int k = 0; k < N; ++k){
      float hv = R[O_H + (b*N + k)*FOUT + f];
      float4 a0 = *(const float4*)&sh[k*4];
      acc[0] += a0.x*hv; acc[1] += a0.y*hv; acc[2] += a0.z*hv; acc[3] += a0.w*hv;
    }
    #pragma unroll
    for (int r = 0; r < 4; ++r)
      ws[O_H1 + (b*N + i0 + r)*FOUT + f] = acc[r];
  }
}

// K4: out = elu(cat(lrelu(rf), lrelu(rb), h1) @ fco_w + fco_b), 4 rows/block, 512 blocks
__global__ __launch_bounds__(256, 2) void k_out(const void* __restrict__ xr,
                                                const void* __restrict__ fcowp,
                                                const void* __restrict__ fcobp,
                                                const float* __restrict__ R, void* dout){
  int blk = blockIdx.x, tid = threadIdx.x;
  int b = blk >> 5, i0 = (blk & 31) * 4;
  constexpr int KW = 2*CI + FOUT;  // 416
  __shared__ __align__(16) float inl[4*KW];
  int mode = blk_mode(xr, 256, tid);
  for (int t = tid; t < 4*2*CI; t += 256){
    int r = t >> 7, k = t & 127;
    int row = b*N + i0 + r;
    inl[r*KW + k] = (k < CI) ? lrelu(R[O_RF + row*CI + k])
                             : lrelu(R[O_RB + row*CI + (k - CI)]);
  }
  for (int t = tid; t < 4*FOUT; t += 256){
    int r = t >> 8, k = t & 255;
    inl[r*KW + 2*CI + k] = R[O_H1 + (b*N + i0 + r)*FOUT + k];
  }
  __syncthreads();
  int l = tid;
  float bias = ldf(fcobp, l, mode);
  float acc[4];
  #pragma unroll
  for (int r = 0; r < 4; ++r) acc[r] = bias;
  if (mode){
    const unsigned short* fu = (const unsigned short*)fcowp;
    #pragma unroll 4
    for (int k = 0; k < KW; k += 4){
      float w0 = bf16_to_f32(fu[(k+0)*L1 + l]);
      float w1 = bf16_to_f32(fu[(k+1)*L1 + l]);
      float w2 = bf16_to_f32(fu[(k+2)*L1 + l]);
      float w3 = bf16_to_f32(fu[(k+3)*L1 + l]);
      #pragma unroll
      for (int r = 0; r < 4; ++r){
        float4 v = *(const float4*)&inl[r*KW + k];
        acc[r] += v.x*w0 + v.y*w1 + v.z*w2 + v.w*w3;
      }
    }
  } else {
    const float* ff = (const float*)fcowp;
    #pragma unroll 4
    for (int k = 0; k < KW; k += 4){
      float w0 = ff[(k+0)*L1 + l];
      float w1 = ff[(k+1)*L1 + l];
      float w2 = ff[(k+2)*L1 + l];
      float w3 = ff[(k+3)*L1 + l];
      #pragma unroll
      for (int r = 0; r < 4; ++r){
        float4 v = *(const float4*)&inl[r*KW + k];
        acc[r] += v.x*w0 + v.y*w1 + v.z*w2 + v.w*w3;
      }
    }
  }
  #pragma unroll
  for (int r = 0; r < 4; ++r){
    float o = acc[r] > 0.f ? acc[r] : expm1f(acc[r]);
    int idx = (b*N + i0 + r)*L1 + l;
    if (mode) ((__hip_bfloat16*)dout)[idx] = __float2bfloat16(o);
    else      ((float*)dout)[idx] = o;
  }
}

extern "C" void kernel_launch(void* const* d_in, const int* in_sizes, int n_in,
                              void* d_out, int out_size, void* d_ws, size_t ws_size,
                              hipStream_t stream){
  (void)n_in; (void)out_size; (void)ws_size;
  float* ws = (float*)d_ws;
  AttArgs A;
  A.we = d_in[2]; A.x = d_in[0]; A.wfcw = d_in[5]; A.wfcb = d_in[6];
  A.fcw = d_in[7]; A.fcb = d_in[8]; A.fccb = d_in[10];
  A.wihf = d_in[11]; A.bihf = d_in[13]; A.bhhf = d_in[14];
  A.wihb = d_in[15]; A.bihb = d_in[17]; A.bhhb = d_in[18];

  // L3-warming prefetch set: inputs consumed by K2/K3/K4 (L3 is poison-evicted
  // every iteration). {ptr, bytes_if_f32, bytes_if_bf16, harness size (clamp)}
  PF pf;
  const int idxs[7]  = {2, 1, 19, 11, 12, 15, 16};
  const int elems[7] = {B*N*N*BINW, B*N*N, (2*CI+FOUT)*L1, CI*N, CI*CI, CI*N, CI*CI};
  const bool isint[7]= {false, true, false, false, false, false, false};
  for (int e = 0; e < 7; ++e){
    pf.p[e]    = d_in[idxs[e]];
    pf.b32[e]  = elems[e]*4;
    pf.b16[e]  = isint[e] ? elems[e]*4 : elems[e]*2;
    pf.insz[e] = in_sizes ? in_sizes[idxs[e]] : 0;
  }

  hipLaunchKernelGGL(k_h_pq,   dim3(1024),   dim3(256), 0, stream,
                     d_in[0], d_in[3], d_in[4], d_in[9], d_in[7], pf, ws);
  hipLaunchKernelGGL(k_att,    dim3(B*N/2),  dim3(256), 0, stream, A, (const int*)d_in[1], ws);
  hipLaunchKernelGGL(k_rnn_h1, dim3(544),    dim3(256), 0, stream,
                     d_in[0], d_in[12], d_in[16], ws);
  hipLaunchKernelGGL(k_out,    dim3(512),    dim3(256), 0, stream,
                     d_in[0], d_in[19], d_in[20], ws, d_out);
}

// Round 4
// 197.774 us; speedup vs baseline: 2.0083x; 1.0730x over previous
//
#include <hip/hip_runtime.h>
#include <hip/hip_bf16.h>

#define DEV static __device__ __forceinline__

constexpr int B=16, N=128, FIN=128, FOUT=256, EOUT=64, BINW=14, BOUT=64, CI=64, L1=256;

// ---- scratch layout in d_ws (float offsets) ----
constexpr int O_H   = 0;                       // [B,N,FOUT]
constexpr int O_S   = O_H  + B*N*FOUT;         // [B,N]
constexpr int O_SU  = O_S  + B*N;
constexpr int O_SV  = O_SU + B*N;
constexpr int O_ATT = O_SV + B*N;              // [B,N,N]
constexpr int O_ZF  = O_ATT+ B*N*N;            // [B,N,CI]
constexpr int O_ZB  = O_ZF + B*N*CI;
constexpr int O_RF  = O_ZB + B*N*CI;
constexpr int O_RB  = O_RF + B*N*CI;
constexpr int O_H1  = O_RB + B*N*CI;           // [B,N,L1] : partial = h1@fco_w[2CI:,:] + fco_b

DEV float bf16_to_f32(unsigned short u){
  unsigned int x = ((unsigned int)u) << 16; float f;
  __builtin_memcpy(&f, &x, 4); return f;
}
DEV void bf2x(unsigned int u, float& lo, float& hi){
  unsigned int a = u << 16, b = u & 0xFFFF0000u;
  __builtin_memcpy(&lo, &a, 4); __builtin_memcpy(&hi, &b, 4);
}
DEV float lrelu(float x){ return x > 0.f ? x : 0.01f * x; }
DEV float bcastf(float v, int lane){
  return __builtin_bit_cast(float, __builtin_amdgcn_readlane(__builtin_bit_cast(int, v), lane));
}
DEV float ldf(const void* p, int i, int m){
  return m ? bf16_to_f32(((const unsigned short*)p)[i]) : ((const float*)p)[i];
}
// block-parallel dtype detect (bf16 ~100% of sampled exps in [100,140]; f32 ~58%)
DEV int blk_mode(const void* x, int nt, int tid){
  const unsigned short* u = (const unsigned short*)x;
  int e = (u[tid & 255] >> 7) & 0xFF;
  int cnt = __syncthreads_count(e >= 100 && e <= 140);
  return cnt * 4 >= nt * 3;
}

// K1: h = x@W ; s = h·fcc_w ; P,Q (LDS only) ; su/sv fused (sv[r]==sv[r+64])
// 512 blocks x 4 rows: 2 blocks/CU.
__global__ __launch_bounds__(256, 2) void k_h_pq(const void* __restrict__ xr,
                                                 const void* __restrict__ Wp,
                                                 const void* __restrict__ Ap,
                                                 const void* __restrict__ fccwp,
                                                 const void* __restrict__ fcwp,
                                                 float* __restrict__ ws){
  int blk = blockIdx.x, tid = threadIdx.x;
  int b = blk >> 5, i0 = (blk & 31) * 4;
  __shared__ __align__(16) float xl[4*FIN];
  __shared__ __align__(16) float hrow[4*FOUT];
  __shared__ __align__(16) float pl[4*EOUT];
  __shared__ __align__(16) float ql[4*EOUT];
  __shared__ float red[16];
  int mode = blk_mode(xr, 256, tid);
  if (mode){
    const unsigned short* xu = (const unsigned short*)xr + (size_t)(b*N + i0)*FIN;
    for (int t = tid; t < 4*FIN/8; t += 256){
      uint4 u4 = ((const uint4*)xu)[t];
      float* o = &xl[t*8];
      bf2x(u4.x,o[0],o[1]); bf2x(u4.y,o[2],o[3]); bf2x(u4.z,o[4],o[5]); bf2x(u4.w,o[6],o[7]);
    }
  } else {
    const float* xf = (const float*)xr + (size_t)(b*N + i0)*FIN;
    for (int t4 = tid; t4 < 4*FIN/4; t4 += 256)
      *(float4*)&xl[t4*4] = ((const float4*)xf)[t4];
  }
  __syncthreads();
  int f = tid;
  float acc[4] = {0,0,0,0};
  if (mode){
    const unsigned short* Wu = (const unsigned short*)Wp;
    #pragma unroll 2
    for (int c = 0; c < FIN; c += 4){
      float w0 = bf16_to_f32(Wu[(c+0)*FOUT + f]);
      float w1 = bf16_to_f32(Wu[(c+1)*FOUT + f]);
      float w2 = bf16_to_f32(Wu[(c+2)*FOUT + f]);
      float w3 = bf16_to_f32(Wu[(c+3)*FOUT + f]);
      #pragma unroll
      for (int r = 0; r < 4; ++r){
        float4 x4 = *(const float4*)&xl[r*FIN + c];
        acc[r] += x4.x*w0 + x4.y*w1 + x4.z*w2 + x4.w*w3;
      }
    }
  } else {
    const float* Wf = (const float*)Wp;
    #pragma unroll 2
    for (int c = 0; c < FIN; c += 4){
      float w0 = Wf[(c+0)*FOUT + f];
      float w1 = Wf[(c+1)*FOUT + f];
      float w2 = Wf[(c+2)*FOUT + f];
      float w3 = Wf[(c+3)*FOUT + f];
      #pragma unroll
      for (int r = 0; r < 4; ++r){
        float4 x4 = *(const float4*)&xl[r*FIN + c];
        acc[r] += x4.x*w0 + x4.y*w1 + x4.z*w2 + x4.w*w3;
      }
    }
  }
  float fw = ldf(fccwp, f, mode);
  #pragma unroll
  for (int r = 0; r < 4; ++r){
    ws[O_H + (b*N + i0 + r)*FOUT + f] = acc[r];
    hrow[r*FOUT + f] = acc[r];
  }
  #pragma unroll
  for (int r = 0; r < 4; ++r){
    float v = acc[r] * fw;
    for (int off = 32; off; off >>= 1) v += __shfl_down(v, off);
    if ((tid & 63) == 0) red[(tid >> 6)*4 + r] = v;
  }
  __syncthreads();
  if (tid < 4){
    float s = red[tid] + red[4+tid] + red[8+tid] + red[12+tid];
    ws[O_S + b*N + i0 + tid] = s;
  }
  // P/Q into LDS (4 waves: which = P/Q, hh = row-half); hrow reads wave-uniform
  {
    int o = tid & 63, which = (tid >> 6) & 1, hh = tid >> 7;
    float a2[2] = {0.f,0.f};
    if (mode){
      const unsigned short* Au = (const unsigned short*)Ap;
      #pragma unroll 2
      for (int c = 0; c < FOUT; c += 4){
        float w0 = bf16_to_f32(Au[(which*FOUT + c+0)*EOUT + o]);
        float w1 = bf16_to_f32(Au[(which*FOUT + c+1)*EOUT + o]);
        float w2 = bf16_to_f32(Au[(which*FOUT + c+2)*EOUT + o]);
        float w3 = bf16_to_f32(Au[(which*FOUT + c+3)*EOUT + o]);
        #pragma unroll
        for (int r = 0; r < 2; ++r){
          float4 h4 = *(const float4*)&hrow[(hh*2+r)*FOUT + c];
          a2[r] += h4.x*w0 + h4.y*w1 + h4.z*w2 + h4.w*w3;
        }
      }
    } else {
      const float* Af = (const float*)Ap;
      #pragma unroll 2
      for (int c = 0; c < FOUT; c += 4){
        float w0 = Af[(which*FOUT + c+0)*EOUT + o];
        float w1 = Af[(which*FOUT + c+1)*EOUT + o];
        float w2 = Af[(which*FOUT + c+2)*EOUT + o];
        float w3 = Af[(which*FOUT + c+3)*EOUT + o];
        #pragma unroll
        for (int r = 0; r < 2; ++r){
          float4 h4 = *(const float4*)&hrow[(hh*2+r)*FOUT + c];
          a2[r] += h4.x*w0 + h4.y*w1 + h4.z*w2 + h4.w*w3;
        }
      }
    }
    float* dst = which ? ql : pl;
    #pragma unroll
    for (int r = 0; r < 2; ++r) dst[(hh*2+r)*EOUT + o] = a2[r];
  }
  __syncthreads();
  // su for rows i0..i0+3 ; sv for pairs (value keyed by j2=(2r)&127; sv[r]==sv[r+64])
  {
    int o = tid & 63, w = tid >> 6;
    float fw2 = ldf(fcwp, o, mode);
    int w2 = (w < 2) ? w : 0;            // waves 2,3 compute a dummy s3 (not stored)
    float s1 = lrelu(pl[w*EOUT + o]        + ql[w*EOUT + o])        * fw2;
    float s3 = lrelu(pl[(2*w2)*EOUT + o]   + ql[(2*w2+1)*EOUT + o]) * fw2;
    for (int off = 32; off; off >>= 1){
      s1 += __shfl_down(s1, off); s3 += __shfl_down(s3, off);
    }
    if (o == 0){
      ws[O_SU + b*N + i0 + w] = s1;
      if (w < 2){
        int r1 = (i0 >> 1) + w;
        ws[O_SV + b*N + r1]      = s3;
        ws[O_SV + b*N + r1 + 64] = s3;
      }
    }
  }
}

struct AttArgs { const void *we,*x,*wfcw,*wfcb,*fcw,*fcb,*fccb,*wihf,*bihf,*bhhf,*wihb,*bihb,*bhhb; };

// K2: per block: TWO (b,i) rows. edge-MLP + mask + softmax -> att ; hn_pre ; z
__global__ __launch_bounds__(256) void k_att(AttArgs A, const int* __restrict__ adj,
                                             float* __restrict__ ws){
  int blk = blockIdx.x, tid = threadIdx.x;
  int half = tid >> 7, j = tid & 127, wv = (tid >> 6) & 1;
  int tau = blk*2 + half;
  int b = tau >> 7, i = tau & 127;
  __shared__ __align__(16) float wel[2][N*BINW];
  __shared__ __align__(16) float hnp[2][N];
  __shared__ __align__(16) float wfcwl[BINW*BOUT];
  __shared__ __align__(16) float wfcbl[BOUT];
  __shared__ __align__(16) float fcw2l[BOUT];
  __shared__ float red2[2][2];
  int mode = blk_mode(A.x, 256, tid);
  for (int t = tid; t < BINW*BOUT; t += 256) wfcwl[t] = ldf(A.wfcw, t, mode);
  if (tid < BOUT){ wfcbl[tid] = ldf(A.wfcb, tid, mode); fcw2l[tid] = ldf(A.fcw, EOUT + tid, mode); }
  if (mode){
    const unsigned short* weu = (const unsigned short*)A.we + (size_t)(b*N + i)*N*BINW;
    for (int t = j; t < N*BINW/8; t += 128){
      uint4 q = ((const uint4*)weu)[t];
      float* o = &wel[half][t*8];
      bf2x(q.x,o[0],o[1]); bf2x(q.y,o[2],o[3]); bf2x(q.z,o[4],o[5]); bf2x(q.w,o[6],o[7]);
    }
  } else {
    const float* wef = (const float*)A.we + (size_t)(b*N + i)*N*BINW;
    for (int t4 = j; t4 < N*BINW/4; t4 += 128)
      *(float4*)&wel[half][t4*4] = ((const float4*)wef)[t4];
  }
  __syncthreads();
  float wr[BINW];
  #pragma unroll
  for (int t = 0; t < BINW; ++t) wr[t] = wel[half][j*BINW + t];
  float wcon = 0.f;
  for (int o = 0; o < BOUT; o += 4){
    float4 bb = *(const float4*)&wfcbl[o];
    float w0 = bb.x, w1 = bb.y, w2 = bb.z, w3 = bb.w;
    #pragma unroll
    for (int t = 0; t < BINW; ++t){
      float4 w4 = *(const float4*)&wfcwl[t*BOUT + o];
      w0 = fmaf(wr[t], w4.x, w0); w1 = fmaf(wr[t], w4.y, w1);
      w2 = fmaf(wr[t], w4.z, w2); w3 = fmaf(wr[t], w4.w, w3);
    }
    float4 f4 = *(const float4*)&fcw2l[o];
    wcon += lrelu(w0)*f4.x + lrelu(w1)*f4.y + lrelu(w2)*f4.z + lrelu(w3)*f4.w;
  }
  const float* R = ws;
  float econ = (i < 64) ? R[O_SU + b*N + 2*i + (j >= 64 ? 1 : 0)]
                        : R[O_SV + b*N + j];
  float etot = econ + wcon + ldf(A.fcb, 0, mode);
  float m = (adj[(b*N + i)*N + j] > 0) ? etot : -9e15f;
  float mx = m;
  for (int off = 32; off; off >>= 1) mx = fmaxf(mx, __shfl_xor(mx, off));
  if ((tid & 63) == 0) red2[half][wv] = mx;
  __syncthreads();
  mx = fmaxf(red2[half][0], red2[half][1]);
  float ev = expf(m - mx);
  float sum = ev;
  for (int off = 32; off; off >>= 1) sum += __shfl_xor(sum, off);
  __syncthreads();
  if ((tid & 63) == 0) red2[half][wv] = sum;
  __syncthreads();
  sum = red2[half][0] + red2[half][1];
  float att = ev / sum;
  ws[O_ATT + (b*N + i)*N + j] = att;
  float sbi = R[O_S + b*N + i];
  hnp[half][j] = lrelu(att * sbi + ldf(A.fccb, 0, mode));
  __syncthreads();
  // z[b,i,c] both directions (per half: 2 waves = 2 directions)
  {
    int d = wv, c = tid & 63;
    float acc = ldf(d ? A.bihb : A.bihf, c, mode) + ldf(d ? A.bhhb : A.bhhf, c, mode);
    const void* wihp = d ? A.wihb : A.wihf;
    if (mode){
      const uint4* wq = (const uint4*)((const unsigned short*)wihp + c*N);
      #pragma unroll 4
      for (int k = 0; k < N; k += 8){
        uint4 q = wq[k >> 3];
        float w0,w1,w2,w3,w4,w5,w6,w7;
        bf2x(q.x,w0,w1); bf2x(q.y,w2,w3); bf2x(q.z,w4,w5); bf2x(q.w,w6,w7);
        float4 h0 = *(const float4*)&hnp[half][k];
        float4 h1 = *(const float4*)&hnp[half][k+4];
        acc += h0.x*w0 + h0.y*w1 + h0.z*w2 + h0.w*w3
             + h1.x*w4 + h1.y*w5 + h1.z*w6 + h1.w*w7;
      }
    } else {
      const float* wf = (const float*)wihp + c*N;
      #pragma unroll 8
      for (int k = 0; k < N; k += 4){
        float4 h4 = *(const float4*)&hnp[half][k];
        float4 w4 = *(const float4*)&wf[k];
        acc += h4.x*w4.x + h4.y*w4.y + h4.z*w4.z + h4.w*w4.w;
      }
    }
    ws[(d ? O_ZB : O_ZF) + (b*N + i)*CI + c] = acc;
  }
}

// K3: blocks 0..31: serial RNN chains (wave 0).
//     blocks 32..543: h1 = att@h (4 rows) FUSED with partial = h1@fco_w[2CI:,:]+fco_b.
// The partial GEMM (2/3 of old K4's work) hides under the RNN chains' latency.
__global__ __launch_bounds__(256, 1) void k_rnn_h1(const void* __restrict__ xr,
                                                   const void* __restrict__ whhf,
                                                   const void* __restrict__ whhb,
                                                   const void* __restrict__ fcowp,
                                                   const void* __restrict__ fcobp,
                                                   float* __restrict__ ws){
  __shared__ __align__(16) float sh[N*CI];   // rnn: 32 KB; h1: attT (512) + h1 rows (1024)
  int blk = blockIdx.x, tid = threadIdx.x;
  int mode = blk_mode(xr, 256, tid);
  const float* R = ws;
  if (blk < 32){
    int d = blk >> 4, b = blk & 15;
    const int zb = (d ? O_ZB : O_ZF) + b*N*CI;
    const int ob = (d ? O_RB : O_RF) + b*N*CI;
    for (int it = tid; it < N*CI/4; it += 256)
      *(float4*)&sh[it*4] = *(const float4*)&ws[zb + it*4];
    __syncthreads();
    if (tid < 64){
      int c = tid;
      const void* whhp = d ? whhb : whhf;
      float wreg[CI];
      if (mode){
        const uint4* wq = (const uint4*)((const unsigned short*)whhp + c*CI);
        #pragma unroll
        for (int k = 0; k < CI; k += 8){
          uint4 q = wq[k >> 3];
          bf2x(q.x,wreg[k+0],wreg[k+1]); bf2x(q.y,wreg[k+2],wreg[k+3]);
          bf2x(q.z,wreg[k+4],wreg[k+5]); bf2x(q.w,wreg[k+6],wreg[k+7]);
        }
      } else {
        const float* wf = (const float*)whhp + c*CI;
        #pragma unroll
        for (int k = 0; k < CI; k += 4){
          float4 w4 = *(const float4*)&wf[k];
          wreg[k]=w4.x; wreg[k+1]=w4.y; wreg[k+2]=w4.z; wreg[k+3]=w4.w;
        }
      }
      const int step = d ? -1 : 1;
      int tt = d ? (N-1) : 0;
      float hv = 0.f;
      float z = sh[tt*CI + c];    // single wave: DS ops in-order, no barrier needed
      for (int t = 0; t < N; ++t){
        int ti = tt + step; ti = ti < 0 ? 0 : (ti > N-1 ? N-1 : ti);
        float znext = sh[ti*CI + c];
        float s[CI];
        #pragma unroll
        for (int k = 0; k < CI; ++k) s[k] = bcastf(hv, k);   // batched readlanes
#if __has_builtin(__builtin_amdgcn_sched_barrier)
        __builtin_amdgcn_sched_barrier(0);
#endif
        float a0 = z, a1 = 0.f, a2 = 0.f, a3 = 0.f;
        #pragma unroll
        for (int k = 0; k < CI; k += 4){
          a0 = fmaf(s[k+0], wreg[k+0], a0);
          a1 = fmaf(s[k+1], wreg[k+1], a1);
          a2 = fmaf(s[k+2], wreg[k+2], a2);
          a3 = fmaf(s[k+3], wreg[k+3], a3);
        }
        float x = (a0+a1)+(a2+a3);
        x = fminf(15.f, fmaxf(-15.f, x));
        float p = __expf(2.f * x);
        hv = (p - 1.f) * __builtin_amdgcn_rcpf(p + 1.f);
        sh[tt*CI + c] = hv;
        z = znext;
        tt += step;
      }
    }
    __syncthreads();
    for (int it = tid; it < N*CI/4; it += 256)
      *(float4*)&ws[ob + it*4] = *(const float4*)&sh[it*4];
  } else {
    int task = blk - 32;                 // 0..511, 4 rows each
    int b = task >> 5, i0 = (task & 31) * 4;
    int f = tid;
    for (int t = tid; t < 4*N; t += 256){
      int r = t >> 7, k = t & 127;
      sh[k*4 + r] = R[O_ATT + (b*N + i0 + r)*N + k];
    }
    __syncthreads();
    float acc[4] = {0,0,0,0};
    #pragma unroll 4
    for (int k = 0; k < N; ++k){
      float hv = R[O_H + (b*N + k)*FOUT + f];
      float4 a0 = *(const float4*)&sh[k*4];
      acc[0] += a0.x*hv; acc[1] += a0.y*hv; acc[2] += a0.z*hv; acc[3] += a0.w*hv;
    }
    // h1 rows -> LDS, then partial = h1 @ fco_w[2CI:,:] + fco_b  (hidden under RNN)
    float* h1l = sh + 4*N;     // 1024 floats
    #pragma unroll
    for (int r = 0; r < 4; ++r) h1l[r*FOUT + f] = acc[r];
    __syncthreads();
    float bias = ldf(fcobp, f, mode);
    float p4[4] = {bias, bias, bias, bias};
    if (mode){
      const unsigned short* fu = (const unsigned short*)fcowp + (size_t)(2*CI)*L1;
      #pragma unroll 2
      for (int k = 0; k < FOUT; k += 4){
        float w0 = bf16_to_f32(fu[(k+0)*L1 + f]);
        float w1 = bf16_to_f32(fu[(k+1)*L1 + f]);
        float w2 = bf16_to_f32(fu[(k+2)*L1 + f]);
        float w3 = bf16_to_f32(fu[(k+3)*L1 + f]);
        #pragma unroll
        for (int r = 0; r < 4; ++r){
          float4 hv = *(const float4*)&h1l[r*FOUT + k];   // wave-uniform -> LDS broadcast
          p4[r] += hv.x*w0 + hv.y*w1 + hv.z*w2 + hv.w*w3;
        }
      }
    } else {
      const float* ff = (const float*)fcowp + (size_t)(2*CI)*L1;
      #pragma unroll 2
      for (int k = 0; k < FOUT; k += 4){
        float w0 = ff[(k+0)*L1 + f];
        float w1 = ff[(k+1)*L1 + f];
        float w2 = ff[(k+2)*L1 + f];
        float w3 = ff[(k+3)*L1 + f];
        #pragma unroll
        for (int r = 0; r < 4; ++r){
          float4 hv = *(const float4*)&h1l[r*FOUT + k];
          p4[r] += hv.x*w0 + hv.y*w1 + hv.z*w2 + hv.w*w3;
        }
      }
    }
    #pragma unroll
    for (int r = 0; r < 4; ++r)
      ws[O_H1 + (b*N + i0 + r)*L1 + f] = p4[r];
  }
}

// K4 (thin): out = elu(partial + cat(lrelu(rf),lrelu(rb)) @ fco_w[0:2CI,:])
__global__ __launch_bounds__(256, 2) void k_out(const void* __restrict__ xr,
                                                const void* __restrict__ fcowp,
                                                const float* __restrict__ R, void* dout){
  int blk = blockIdx.x, tid = threadIdx.x;
  int b = blk >> 5, i0 = (blk & 31) * 4;
  __shared__ __align__(16) float inl[4*2*CI];   // 4 rows x 128
  int mode = blk_mode(xr, 256, tid);
  for (int t = tid; t < 4*2*CI; t += 256){
    int r = t >> 7, k = t & 127;
    int row = b*N + i0 + r;
    inl[r*128 + k] = (k < CI) ? lrelu(R[O_RF + row*CI + k])
                              : lrelu(R[O_RB + row*CI + (k - CI)]);
  }
  __syncthreads();
  int l = tid;
  float acc[4];
  #pragma unroll
  for (int r = 0; r < 4; ++r) acc[r] = R[O_H1 + (b*N + i0 + r)*L1 + l];  // partial (incl bias+h1 part)
  if (mode){
    const unsigned short* fu = (const unsigned short*)fcowp;
    #pragma unroll 4
    for (int k = 0; k < 2*CI; k += 4){
      float w0 = bf16_to_f32(fu[(k+0)*L1 + l]);
      float w1 = bf16_to_f32(fu[(k+1)*L1 + l]);
      float w2 = bf16_to_f32(fu[(k+2)*L1 + l]);
      float w3 = bf16_to_f32(fu[(k+3)*L1 + l]);
      #pragma unroll
      for (int r = 0; r < 4; ++r){
        float4 v = *(const float4*)&inl[r*128 + k];
        acc[r] += v.x*w0 + v.y*w1 + v.z*w2 + v.w*w3;
      }
    }
  } else {
    const float* ff = (const float*)fcowp;
    #pragma unroll 4
    for (int k = 0; k < 2*CI; k += 4){
      float w0 = ff[(k+0)*L1 + l];
      float w1 = ff[(k+1)*L1 + l];
      float w2 = ff[(k+2)*L1 + l];
      float w3 = ff[(k+3)*L1 + l];
      #pragma unroll
      for (int r = 0; r < 4; ++r){
        float4 v = *(const float4*)&inl[r*128 + k];
        acc[r] += v.x*w0 + v.y*w1 + v.z*w2 + v.w*w3;
      }
    }
  }
  #pragma unroll
  for (int r = 0; r < 4; ++r){
    float o = acc[r] > 0.f ? acc[r] : expm1f(acc[r]);
    int idx = (b*N + i0 + r)*L1 + l;
    if (mode) ((__hip_bfloat16*)dout)[idx] = __float2bfloat16(o);
    else      ((float*)dout)[idx] = o;
  }
}

extern "C" void kernel_launch(void* const* d_in, const int* in_sizes, int n_in,
                              void* d_out, int out_size, void* d_ws, size_t ws_size,
                              hipStream_t stream){
  (void)in_sizes; (void)n_in; (void)out_size; (void)ws_size;
  float* ws = (float*)d_ws;
  AttArgs A;
  A.we = d_in[2]; A.x = d_in[0]; A.wfcw = d_in[5]; A.wfcb = d_in[6];
  A.fcw = d_in[7]; A.fcb = d_in[8]; A.fccb = d_in[10];
  A.wihf = d_in[11]; A.bihf = d_in[13]; A.bhhf = d_in[14];
  A.wihb = d_in[15]; A.bihb = d_in[17]; A.bhhb = d_in[18];
  hipLaunchKernelGGL(k_h_pq,   dim3(512),    dim3(256), 0, stream,
                     d_in[0], d_in[3], d_in[4], d_in[9], d_in[7], ws);
  hipLaunchKernelGGL(k_att,    dim3(B*N/2),  dim3(256), 0, stream, A, (const int*)d_in[1], ws);
  hipLaunchKernelGGL(k_rnn_h1, dim3(544),    dim3(256), 0, stream,
                     d_in[0], d_in[12], d_in[16], d_in[19], d_in[20], ws);
  hipLaunchKernelGGL(k_out,    dim3(512),    dim3(256), 0, stream,
                     d_in[0], d_in[19], ws, d_out);
}